// Round 7
// baseline (315.123 us; speedup 1.0000x reference)
//
#include <hip/hip_runtime.h>
#include <cstdint>
#include <cstddef>

// ---------------------------------------------------------------------------
// GatingNetwork r7: switch GEMM to mfma_f32_32x32x16_f16 (17% faster MFMA
// rate, halves A-fragment LDS reads + ahs VALU vs r6), keep r6's rolling
// B double-set pipeline at k-step granularity, raw lgkm-only barriers,
// 4 waves/SIMD floor-plan (setB 32 VGPR + acc 64 AGPR).
// C/D layout (m74/m101-verified): col=lane&31, row=(reg&3)+8(reg>>2)+4(lane>>5).
// A/B: row/col=lane&31, k=(lane>>5)*8+i (contiguous 8 halves).
// Numerics (r1-r6 verified): A=64x hi/lo fp16, B=64w hi/lo fp16 (lo x2^8);
// 3-product Markidis; h at scale 2^12; fused LN/erf-GELU/top2/lb-loss.
// ---------------------------------------------------------------------------

typedef _Float16 f16;
typedef _Float16 f16x4 __attribute__((ext_vector_type(4)));
typedef _Float16 f16x8 __attribute__((ext_vector_type(8)));
typedef float f32x16 __attribute__((ext_vector_type(16)));

#define B_ROWS 65536
#define D_DIM 1024
#define H_DIM 512
#define E_DIM 8
#define BM 64
#define BK 32
#define THREADS 512
#define NCHUNK 32
#define LDPX 40                          // slab row stride in halves (80 B)
#define SLABH 2560                       // 64 rows x 40 halves (one image)
#define BUFH 5120                        // hi + lo per buffer
#define STEPH (H_DIM * 16)               // 8192 halves per K=16 step image
#define IMG_TOTAL (64 * STEPH)           // 524288 halves = 1 MB per image
#define GACC_OFF ((size_t)2 * IMG_TOTAL * sizeof(f16))  // 2 MB

// ---- prep: split W1 into fp16 hi/lo step-images in 32x32 B-fragment order --
// img[s][col][k'] (s = k/16, k' = k&15): lane reads col*16 + (lane>>5)*8.
__global__ void prep_split(const float* __restrict__ W1,
                           f16* __restrict__ wh, f16* __restrict__ wl) {
  int id = blockIdx.x * 256 + threadIdx.x;   // 65536 threads
  int h = id & (H_DIM - 1);
  int kg = id >> 9;                          // 0..127
  int k0 = kg * 8;
  int s = k0 >> 4;                           // 0..63
  int ko = k0 & 15;                          // 0 or 8
  f16x8 hv, lv;
#pragma unroll
  for (int j = 0; j < 8; ++j) {
    float v = W1[(size_t)(k0 + j) * H_DIM + h] * 64.0f;
    f16 hi = (f16)v;
    hv[j] = hi;
    lv[j] = (f16)((v - (float)hi) * 256.0f);  // residual pre-scaled 2^8
  }
  size_t o = (size_t)s * STEPH + (size_t)h * 16 + ko;
  *(f16x8*)&wh[o] = hv;
  *(f16x8*)&wl[o] = lv;
}

__global__ void zero_acc(float* __restrict__ acc) {
  if (threadIdx.x < 16) acc[threadIdx.x] = 0.0f;
}

// ---- main fused kernel -----------------------------------------------------
__global__ __launch_bounds__(THREADS, 4) void fused_main(
    const float* __restrict__ x,
    const f16* __restrict__ wh, const f16* __restrict__ wl,
    const float* __restrict__ b1, const float* __restrict__ lnw,
    const float* __restrict__ lnb, const float* __restrict__ W2,
    const float* __restrict__ b2, float* __restrict__ out,
    float* __restrict__ gacc) {
  // GEMM uses [0,20480) (2 x-slab buffers). Epilogue overlays [0,21056).
  __shared__ __align__(16) char pool[21056];
  f16* sx = (f16*)pool;

  const int tid = threadIdx.x;
  const int lane = tid & 63;
  const int wv = tid >> 6;        // 0..7 : wave owns cols wv*64..+63, all 64 rows
  const int l31 = lane & 31;
  const int hi5 = lane >> 5;      // 0..1
  const int64_t row0 = (int64_t)blockIdx.x * BM;

  // staging: thread stages row tid>>3, 4 floats at k-offset (tid&7)*4
  const int srow = tid >> 3;
  const int sc4 = (tid & 7) * 4;
  const int swo = srow * LDPX + sc4;
  const float* xbase = x + (row0 + srow) * D_DIM + sc4;

  // B lane base within a step image (32x32 fragment order)
  const int blane = (wv * 64 + l31) * 16 + hi5 * 8;
  const f16* whp = wh + blane;

  f32x16 acc[2][2];
#pragma unroll
  for (int mt = 0; mt < 2; ++mt)
#pragma unroll
    for (int nt = 0; nt < 2; ++nt)
#pragma unroll
      for (int r = 0; r < 16; ++r) acc[mt][nt][r] = 0.0f;

  // two k-step B register sets: [set][0..1]=hi frags (nt0,nt1), [2..3]=lo
  f16x8 setB[2][4];

#define ISSUE(si, G)                                                          \
  do {                                                                        \
    const f16* p = whp + (size_t)((G) & 63) * STEPH;                          \
    setB[si][0] = *(const f16x8*)(p);                                         \
    setB[si][1] = *(const f16x8*)(p + 512);                                   \
    setB[si][2] = *(const f16x8*)(p + IMG_TOTAL);                             \
    setB[si][3] = *(const f16x8*)(p + IMG_TOTAL + 512);                       \
  } while (0)

#define KSTEP(si, ks, bufv)                                                   \
  do {                                                                        \
    __builtin_amdgcn_s_setprio(1);                                            \
    _Pragma("unroll") for (int mt = 0; mt < 2; ++mt) {                        \
      const int ao = (bufv)*BUFH + (mt * 32 + l31) * LDPX + (ks)*16 + hi5 * 8;\
      f16x8 ah = *(const f16x8*)&sx[ao];                                      \
      f16x8 al = *(const f16x8*)&sx[ao + SLABH];                              \
      f16x8 ahs;                                                              \
      _Pragma("unroll") for (int q = 0; q < 8; ++q) ahs[q] =                  \
          ah[q] * (f16)0.00390625f;                                           \
      acc[mt][0] = __builtin_amdgcn_mfma_f32_32x32x16_f16(                    \
          ah, setB[si][0], acc[mt][0], 0, 0, 0);                              \
      acc[mt][0] = __builtin_amdgcn_mfma_f32_32x32x16_f16(                    \
          al, setB[si][0], acc[mt][0], 0, 0, 0);                              \
      acc[mt][0] = __builtin_amdgcn_mfma_f32_32x32x16_f16(                    \
          ahs, setB[si][2], acc[mt][0], 0, 0, 0);                             \
      acc[mt][1] = __builtin_amdgcn_mfma_f32_32x32x16_f16(                    \
          ah, setB[si][1], acc[mt][1], 0, 0, 0);                              \
      acc[mt][1] = __builtin_amdgcn_mfma_f32_32x32x16_f16(                    \
          al, setB[si][1], acc[mt][1], 0, 0, 0);                              \
      acc[mt][1] = __builtin_amdgcn_mfma_f32_32x32x16_f16(                    \
          ahs, setB[si][3], acc[mt][1], 0, 0, 0);                             \
    }                                                                         \
    __builtin_amdgcn_s_setprio(0);                                            \
  } while (0)

#define WRITE_SLAB(bufv)                                                      \
  do {                                                                        \
    float vv[4] = {xv.x, xv.y, xv.z, xv.w};                                   \
    f16x4 hv, lv;                                                             \
    _Pragma("unroll") for (int q = 0; q < 4; ++q) {                           \
      float t = vv[q] * 64.0f;                                                \
      f16 hh = (f16)t;                                                        \
      hv[q] = hh;                                                             \
      lv[q] = (f16)(t - (float)hh);                                           \
    }                                                                         \
    *(f16x4*)&sx[(bufv)*BUFH + swo] = hv;                                     \
    *(f16x4*)&sx[(bufv)*BUFH + SLABH + swo] = lv;                             \
  } while (0)

  // raw barrier: drain only LDS ops, keep global loads in flight (T4)
#define SLAB_BARRIER()                                                        \
  do {                                                                        \
    asm volatile("s_waitcnt lgkmcnt(0)" ::: "memory");                        \
    __builtin_amdgcn_s_barrier();                                             \
    __builtin_amdgcn_sched_barrier(0);                                        \
  } while (0)

  // ---- prologue: slab chunk0, B sets for steps 0/1, xv <- chunk1 ----------
  float4 xv = *(const float4*)(xbase);
  WRITE_SLAB(0);
  ISSUE(0, 0);
  ISSUE(1, 1);
  xv = *(const float4*)(xbase + 32);
  SLAB_BARRIER();

  for (int c = 0; c < NCHUNK; ++c) {
    const int buf = c & 1;
    KSTEP(0, 0, buf);             // step 2c   (set issued ~1 chunk ago)
    ISSUE(0, 2 * c + 2);          // refill set0 for step 2c+2
    KSTEP(1, 1, buf);             // step 2c+1
    ISSUE(1, 2 * c + 3);          // refill set1 for step 2c+3
    WRITE_SLAB(buf ^ 1);          // slab chunk c+1 (xv loaded last iteration)
    xv = *(const float4*)(xbase + ((c + 2) & 31) * 32);  // x for chunk c+2
    SLAB_BARRIER();
  }
#undef ISSUE
#undef KSTEP
#undef WRITE_SLAB
#undef SLAB_BARRIER
  __syncthreads();  // full drain before overlaying epilogue LDS

  // ---------------- epilogue (h at scale 2^12 in acc) -----------------------
  // C/D map: row = (reg&3) + 8*(reg>>2) + 4*hi5 + 32*mt, col = wv*64+nt*32+l31
  float* eStat = (float*)pool;             // [8][64][2] = 4096 B
  float* eLog = (float*)(pool + 4096);     // [8][64][8] = 16384 B
  float* eMu = (float*)(pool + 20480);     // [64]
  float* eRs = (float*)(pool + 20736);     // [64]
  float* eFP = (float*)(pool + 20992);     // [16]

  // per-column params from L2 (2 cols per thread)
  float bb[2], lw[2], lb[2];
  float4 w2a[2], w2b[2];
#pragma unroll
  for (int nt = 0; nt < 2; ++nt) {
    int col = wv * 64 + nt * 32 + l31;
    bb[nt] = b1[col] * 4096.0f;
    lw[nt] = lnw[col];
    lb[nt] = lnb[col];
    w2a[nt] = *(const float4*)&W2[col * 8];
    w2b[nt] = *(const float4*)&W2[col * 8 + 4];
  }
  if (tid < 16) eFP[tid] = 0.0f;

  // h += b1 (scaled)
#pragma unroll
  for (int mt = 0; mt < 2; ++mt)
#pragma unroll
    for (int nt = 0; nt < 2; ++nt)
#pragma unroll
      for (int r = 0; r < 16; ++r) acc[mt][nt][r] += bb[nt];

  // row stats: per (mt, q-group of 4 regs), 5-step shfl over l31, write once
#pragma unroll
  for (int mt = 0; mt < 2; ++mt)
#pragma unroll
    for (int q = 0; q < 4; ++q) {
      float s1[4], s2[4];
#pragma unroll
      for (int r = 0; r < 4; ++r) {
        float v0 = acc[mt][0][q * 4 + r];
        float v1 = acc[mt][1][q * 4 + r];
        s1[r] = v0 + v1;
        s2[r] = fmaf(v0, v0, v1 * v1);
      }
#pragma unroll
      for (int d = 1; d < 32; d <<= 1)
#pragma unroll
        for (int r = 0; r < 4; ++r) {
          s1[r] += __shfl_xor(s1[r], d);
          s2[r] += __shfl_xor(s2[r], d);
        }
      if (l31 == 0) {
        int rb = 8 * q + 4 * hi5 + 32 * mt;
#pragma unroll
        for (int r = 0; r < 4; ++r) {
          eStat[(wv * 64 + rb + r) * 2 + 0] = s1[r];
          eStat[(wv * 64 + rb + r) * 2 + 1] = s2[r];
        }
      }
    }
  __syncthreads();
  if (tid < BM) {
    float s1 = 0.0f, s2 = 0.0f;
#pragma unroll
    for (int w = 0; w < 8; ++w) {
      s1 += eStat[(w * 64 + tid) * 2 + 0];
      s2 += eStat[(w * 64 + tid) * 2 + 1];
    }
    float mu = s1 * (1.0f / 512.0f);
    float var = s2 * (1.0f / 512.0f) - mu * mu;
    eMu[tid] = mu;
    eRs[tid] = 1.0f / sqrtf(var + (1e-5f * 4096.0f * 4096.0f));
  }
  __syncthreads();

  // LN + exact-erf GELU + per-wave partial logits (per-row, 5-step shfl)
#pragma unroll
  for (int mt = 0; mt < 2; ++mt)
#pragma unroll
    for (int q = 0; q < 4; ++q)
#pragma unroll
      for (int r = 0; r < 4; ++r) {
        const int reg = q * 4 + r;
        const int row = r + 8 * q + 4 * hi5 + 32 * mt;
        float mu_r = eMu[row];
        float rs_r = eRs[row];
        float lg[8];
#pragma unroll
        for (int e = 0; e < 8; ++e) lg[e] = 0.0f;
#pragma unroll
        for (int nt = 0; nt < 2; ++nt) {
          float hn = (acc[mt][nt][reg] - mu_r) * rs_r;
          float y = fmaf(hn, lw[nt], lb[nt]);
          float g = 0.5f * y * (1.0f + erff(y * 0.70710678118654752440f));
          lg[0] = fmaf(g, w2a[nt].x, lg[0]);
          lg[1] = fmaf(g, w2a[nt].y, lg[1]);
          lg[2] = fmaf(g, w2a[nt].z, lg[2]);
          lg[3] = fmaf(g, w2a[nt].w, lg[3]);
          lg[4] = fmaf(g, w2b[nt].x, lg[4]);
          lg[5] = fmaf(g, w2b[nt].y, lg[5]);
          lg[6] = fmaf(g, w2b[nt].z, lg[6]);
          lg[7] = fmaf(g, w2b[nt].w, lg[7]);
        }
#pragma unroll
        for (int d = 1; d < 32; d <<= 1)
#pragma unroll
          for (int e = 0; e < 8; ++e) lg[e] += __shfl_xor(lg[e], d);
        if (l31 == 0) {
#pragma unroll
          for (int e = 0; e < 8; ++e) eLog[(wv * 64 + row) * 8 + e] = lg[e];
        }
      }
  __syncthreads();

  // top-2 + sparse softmax + write + load-balance partials
  if (tid < BM) {
    float v[8];
#pragma unroll
    for (int e = 0; e < 8; ++e) {
      float s = b2[e];
#pragma unroll
      for (int w = 0; w < 8; ++w) s += eLog[(w * 64 + tid) * 8 + e];
      v[e] = s;
    }
    float m1 = v[0];
    int i1 = 0;
#pragma unroll
    for (int e = 1; e < 8; ++e)
      if (v[e] > m1) { m1 = v[e]; i1 = e; }   // strict >: lowest index wins ties
    float m2 = -3.0e38f;
    int i2 = -1;
#pragma unroll
    for (int e = 0; e < 8; ++e)
      if (e != i1 && v[e] > m2) { m2 = v[e]; i2 = e; }
    float dd = expf(m2 - m1);
    float inv = 1.0f / (1.0f + dd);
    float wA = inv, wB = dd * inv;
    float o[8];
#pragma unroll
    for (int e = 0; e < 8; ++e)
      o[e] = (e == i1) ? wA : ((e == i2) ? wB : 0.0f);
    float4* op = (float4*)&out[(row0 + tid) * 8];
    op[0] = (float4){o[0], o[1], o[2], o[3]};
    op[1] = (float4){o[4], o[5], o[6], o[7]};
    atomicAdd(&eFP[i1], 1.0f);
    atomicAdd(&eFP[i2], 1.0f);
    atomicAdd(&eFP[8 + i1], wA);
    atomicAdd(&eFP[8 + i2], wB);
  }
  __syncthreads();
  if (tid < 16) atomicAdd(&gacc[tid], eFP[tid]);
}

// ---- finalize load-balance loss --------------------------------------------
__global__ void lb_final(const float* __restrict__ gacc, float* __restrict__ out) {
  if (threadIdx.x == 0) {
    const float invB = 1.0f / 65536.0f;
    float s = 0.0f;
#pragma unroll
    for (int e = 0; e < 8; ++e) s += (gacc[e] * invB) * (gacc[8 + e] * invB);
    out[(size_t)B_ROWS * E_DIM] = 0.01f * 8.0f * s;
  }
}

// ---- launch ----------------------------------------------------------------
extern "C" void kernel_launch(void* const* d_in, const int* in_sizes, int n_in,
                              void* d_out, int out_size, void* d_ws, size_t ws_size,
                              hipStream_t stream) {
  (void)in_sizes; (void)n_in; (void)out_size; (void)ws_size;
  const float* x = (const float*)d_in[0];
  const float* W1 = (const float*)d_in[1];
  const float* b1 = (const float*)d_in[2];
  const float* lnw = (const float*)d_in[3];
  const float* lnb = (const float*)d_in[4];
  const float* W2 = (const float*)d_in[5];
  const float* b2 = (const float*)d_in[6];
  float* out = (float*)d_out;
  f16* wh = (f16*)d_ws;
  f16* wl = wh + IMG_TOTAL;
  float* gacc = (float*)((char*)d_ws + GACC_OFF);  // ws needs ~2.1 MB

  zero_acc<<<1, 64, 0, stream>>>(gacc);
  prep_split<<<(D_DIM * H_DIM / 8) / 256, 256, 0, stream>>>(W1, wh, wl);
  fused_main<<<B_ROWS / BM, THREADS, 0, stream>>>(x, wh, wl, b1, lnw, lnb, W2, b2,
                                                  out, gacc);
  lb_final<<<1, 64, 0, stream>>>(gacc, out);
}

// Round 8
// 248.865 us; speedup vs baseline: 1.2662x; 1.2662x over previous
//
#include <hip/hip_runtime.h>
#include <cstdint>
#include <cstddef>

// ---------------------------------------------------------------------------
// GatingNetwork r8: r6 engine (16x16x32, rolling 2-set B pipeline, raw
// lgkm-only barriers, 4 waves/SIMD floor-plan) + two fixes from r7 evidence:
// (1) K=64 super-slabs -> barrier every 2 chunks (16 vs 32 drains),
// (2) alternate-accumulator MFMA order (dependent spacing 0 -> ~39 cyc).
// Numerics (r1-r7 verified): A=64x hi/lo fp16, B=64w hi/lo fp16 (lo x2^8);
// 3-product Markidis MFMA 16x16x32; h at scale 2^12; fused LN/GELU/top2.
// ---------------------------------------------------------------------------

typedef _Float16 f16;
typedef _Float16 f16x8 __attribute__((ext_vector_type(8)));
typedef float f32x4 __attribute__((ext_vector_type(4)));

#define B_ROWS 65536
#define D_DIM 1024
#define H_DIM 512
#define E_DIM 8
#define BM 64
#define BK 32
#define THREADS 512
#define NSUPER 16                        // 16 supers x K64 (2 chunks each)
#define LDPX 72                          // slab row stride in halves (144 B)
#define SLABH 4608                       // 64 rows x 72 halves (one image)
#define BUFH 9216                        // hi + lo per buffer
#define IMG_CH (H_DIM * BK)              // 16384 halves per K-chunk B image
#define IMG_TOTAL (32 * IMG_CH)          // 1 MB per image
#define GACC_OFF ((size_t)2 * IMG_TOTAL * sizeof(f16))  // 2 MB

// ---- prep: split W1 into fp16 hi/lo images in MFMA B-fragment order --------
__global__ void prep_split(const float* __restrict__ W1,
                           f16* __restrict__ wh, f16* __restrict__ wl) {
  int id = blockIdx.x * 256 + threadIdx.x;   // 65536 threads
  int h = id & (H_DIM - 1);
  int kg = id >> 9;                          // 0..127
  int c = kg >> 2;
  int kk0 = (kg & 3) * 8;
  int k0 = kg * 8;
  f16x8 hv, lv;
#pragma unroll
  for (int j = 0; j < 8; ++j) {
    float v = W1[(size_t)(k0 + j) * H_DIM + h] * 64.0f;
    f16 hi = (f16)v;
    hv[j] = hi;
    lv[j] = (f16)((v - (float)hi) * 256.0f);  // residual pre-scaled 2^8
  }
  size_t o = (size_t)c * IMG_CH + (size_t)h * BK + kk0;
  *(f16x8*)&wh[o] = hv;
  *(f16x8*)&wl[o] = lv;
}

__global__ void zero_acc(float* __restrict__ acc) {
  if (threadIdx.x < 16) acc[threadIdx.x] = 0.0f;
}

// ---- main fused kernel -----------------------------------------------------
__global__ __launch_bounds__(THREADS, 4) void fused_main(
    const float* __restrict__ x,
    const f16* __restrict__ wh, const f16* __restrict__ wl,
    const float* __restrict__ b1, const float* __restrict__ lnw,
    const float* __restrict__ lnb, const float* __restrict__ W2,
    const float* __restrict__ b2, float* __restrict__ out,
    float* __restrict__ gacc) {
  // GEMM uses [0,36864) (2 K=64 x-slab buffers). Epilogue overlays [0,45632).
  __shared__ __align__(16) char pool[45632];
  f16* sx = (f16*)pool;

  const int tid = threadIdx.x;
  const int lane = tid & 63;
  const int wv = tid >> 6;        // 0..7 : wave owns cols wv*64..+63, all 64 rows
  const int l15 = lane & 15;
  const int l4 = lane >> 4;       // 0..3
  const int64_t row0 = (int64_t)blockIdx.x * BM;

  // staging: thread stages row tid>>3, 8 floats at k-offset (tid&7)*8
  const int srow = tid >> 3;
  const int sk = (tid & 7) * 8;
  const int swo = srow * LDPX + sk;
  const float* xbase = x + (row0 + srow) * D_DIM + sk;

  // B lane base (fragment-order image, r2-verified)
  const f16* whp = wh + (wv * 64 + l15) * BK + l4 * 8;

  f32x4 acc[4][4];
#pragma unroll
  for (int m = 0; m < 4; ++m)
#pragma unroll
    for (int n = 0; n < 4; ++n) acc[m][n] = (f32x4){0.f, 0.f, 0.f, 0.f};

  // two half-chunk B register sets: [set][0..1]=hi frags, [2..3]=lo frags
  f16x8 setB[2][4];

#define ISSUE(si, C, half)                                                    \
  do {                                                                        \
    const f16* p = whp + (size_t)((C) & 31) * IMG_CH + (half) * 1024;         \
    setB[si][0] = *(const f16x8*)(p);                                         \
    setB[si][1] = *(const f16x8*)(p + 512);                                   \
    setB[si][2] = *(const f16x8*)(p + IMG_TOTAL);                             \
    setB[si][3] = *(const f16x8*)(p + IMG_TOTAL + 512);                       \
  } while (0)

  // alternate-accumulator order: dependent MFMAs on one acc are spaced by one
  // intervening MFMA (~39 SIMD-cyc) instead of back-to-back.
#define CHUNK_HALF(si, nh, ch, bufv)                                          \
  do {                                                                        \
    __builtin_amdgcn_s_setprio(1);                                            \
    _Pragma("unroll") for (int m = 0; m < 4; ++m) {                           \
      const int ao = (bufv)*BUFH + (m * 16 + l15) * LDPX + (ch)*32 + l4 * 8;  \
      f16x8 ah = *(const f16x8*)&sx[ao];                                      \
      f16x8 al = *(const f16x8*)&sx[ao + SLABH];                              \
      f16x8 ahs;                                                              \
      _Pragma("unroll") for (int q = 0; q < 8; ++q) ahs[q] =                  \
          ah[q] * (f16)0.00390625f;                                           \
      acc[m][(nh)*2 + 0] = __builtin_amdgcn_mfma_f32_16x16x32_f16(            \
          ah, setB[si][0], acc[m][(nh)*2 + 0], 0, 0, 0);                      \
      acc[m][(nh)*2 + 1] = __builtin_amdgcn_mfma_f32_16x16x32_f16(            \
          ah, setB[si][1], acc[m][(nh)*2 + 1], 0, 0, 0);                      \
      acc[m][(nh)*2 + 0] = __builtin_amdgcn_mfma_f32_16x16x32_f16(            \
          al, setB[si][0], acc[m][(nh)*2 + 0], 0, 0, 0);                      \
      acc[m][(nh)*2 + 1] = __builtin_amdgcn_mfma_f32_16x16x32_f16(            \
          al, setB[si][1], acc[m][(nh)*2 + 1], 0, 0, 0);                      \
      acc[m][(nh)*2 + 0] = __builtin_amdgcn_mfma_f32_16x16x32_f16(            \
          ahs, setB[si][2], acc[m][(nh)*2 + 0], 0, 0, 0);                     \
      acc[m][(nh)*2 + 1] = __builtin_amdgcn_mfma_f32_16x16x32_f16(            \
          ahs, setB[si][3], acc[m][(nh)*2 + 1], 0, 0, 0);                     \
    }                                                                         \
    __builtin_amdgcn_s_setprio(0);                                            \
  } while (0)

#define WRITE_SLAB(bufv)                                                      \
  do {                                                                        \
    float vv[8] = {xv0.x, xv0.y, xv0.z, xv0.w, xv1.x, xv1.y, xv1.z, xv1.w};   \
    f16x8 hv, lv;                                                             \
    _Pragma("unroll") for (int q = 0; q < 8; ++q) {                           \
      float t = vv[q] * 64.0f;                                                \
      f16 hh = (f16)t;                                                        \
      hv[q] = hh;                                                             \
      lv[q] = (f16)(t - (float)hh);                                           \
    }                                                                         \
    *(f16x8*)&sx[(bufv)*BUFH + swo] = hv;                                     \
    *(f16x8*)&sx[(bufv)*BUFH + SLABH + swo] = lv;                             \
  } while (0)

  // raw barrier: drain only LDS ops, keep global loads in flight (T4)
#define SLAB_BARRIER()                                                        \
  do {                                                                        \
    asm volatile("s_waitcnt lgkmcnt(0)" ::: "memory");                        \
    __builtin_amdgcn_s_barrier();                                             \
    __builtin_amdgcn_sched_barrier(0);                                        \
  } while (0)

  // ---- prologue: slab super0, B sets for chunk0 halves, xv <- super1 ------
  float4 xv0 = *(const float4*)(xbase);
  float4 xv1 = *(const float4*)(xbase + 4);
  WRITE_SLAB(0);
  ISSUE(0, 0, 0);
  ISSUE(1, 0, 1);
  xv0 = *(const float4*)(xbase + 64);
  xv1 = *(const float4*)(xbase + 68);
  SLAB_BARRIER();

  for (int s = 0; s < NSUPER; ++s) {
    const int buf = s & 1;
    CHUNK_HALF(0, 0, 0, buf);     // chunk 2s,   frags n0/n1
    ISSUE(0, 2 * s + 1, 0);       // refill set0 for chunk 2s+1
    CHUNK_HALF(1, 1, 0, buf);     // chunk 2s,   frags n2/n3
    ISSUE(1, 2 * s + 1, 1);       // refill set1 for chunk 2s+1
    CHUNK_HALF(0, 0, 1, buf);     // chunk 2s+1, frags n0/n1
    ISSUE(0, 2 * s + 2, 0);       // refill set0 for chunk 2s+2
    CHUNK_HALF(1, 1, 1, buf);     // chunk 2s+1, frags n2/n3
    ISSUE(1, 2 * s + 2, 1);       // refill set1 for chunk 2s+2
    WRITE_SLAB(buf ^ 1);          // slab for super s+1 (xv loaded last iter)
    xv0 = *(const float4*)(xbase + (((s + 2) & 15) * 64));   // x for super s+2
    xv1 = *(const float4*)(xbase + (((s + 2) & 15) * 64) + 4);
    SLAB_BARRIER();
  }
#undef ISSUE
#undef CHUNK_HALF
#undef WRITE_SLAB
#undef SLAB_BARRIER
  __syncthreads();  // full drain before overlaying epilogue LDS

  // ---------------- epilogue (h at scale 2^12 in acc; r6-verified) ----------
  float* eW2T = (float*)pool;              // [512][12] padded = 24576 B
  float* eStat = (float*)(pool + 24576);   // [8][64][2] = 4096 B
  float* eLog = (float*)(pool + 28672);    // [8][64][8] = 16384 B
  float* eMu = (float*)(pool + 45056);     // [64]
  float* eRs = (float*)(pool + 45312);     // [64]
  float* eFP = (float*)(pool + 45568);     // [16]

  // stage W2 (each thread owns one column h = tid)
  {
    float4 wa = *(const float4*)&W2[tid * 8];
    float4 wb = *(const float4*)&W2[tid * 8 + 4];
    *(float4*)&eW2T[tid * 12] = wa;
    *(float4*)&eW2T[tid * 12 + 4] = wb;
  }
  if (tid < 16) eFP[tid] = 0.0f;

  // h += b1 (scaled); per-column params from L2 (tiny + hot)
  float bb[4], lw[4], lb[4];
#pragma unroll
  for (int n = 0; n < 4; ++n) {
    int col = wv * 64 + n * 16 + l15;
    bb[n] = b1[col] * 4096.0f;
    lw[n] = lnw[col];
    lb[n] = lnb[col];
#pragma unroll
    for (int m = 0; m < 4; ++m)
#pragma unroll
      for (int r = 0; r < 4; ++r) acc[m][n][r] += bb[n];
  }

  // row stats: partial over this wave's 64 cols, deterministic combine
#pragma unroll
  for (int m = 0; m < 4; ++m) {
    float s1[4] = {0, 0, 0, 0};
    float s2[4] = {0, 0, 0, 0};
#pragma unroll
    for (int n = 0; n < 4; ++n)
#pragma unroll
      for (int r = 0; r < 4; ++r) {
        float vv = acc[m][n][r];
        s1[r] += vv;
        s2[r] = fmaf(vv, vv, s2[r]);
      }
#pragma unroll
    for (int d = 1; d < 16; d <<= 1)
#pragma unroll
      for (int r = 0; r < 4; ++r) {
        s1[r] += __shfl_xor(s1[r], d);
        s2[r] += __shfl_xor(s2[r], d);
      }
    if (l15 == 0) {
      int rb = m * 16 + l4 * 4;
#pragma unroll
      for (int r = 0; r < 4; ++r) {
        eStat[(wv * 64 + rb + r) * 2 + 0] = s1[r];
        eStat[(wv * 64 + rb + r) * 2 + 1] = s2[r];
      }
    }
  }
  __syncthreads();
  if (tid < BM) {
    float s1 = 0.0f, s2 = 0.0f;
#pragma unroll
    for (int w = 0; w < 8; ++w) {
      s1 += eStat[(w * 64 + tid) * 2 + 0];
      s2 += eStat[(w * 64 + tid) * 2 + 1];
    }
    float mu = s1 * (1.0f / 512.0f);
    float var = s2 * (1.0f / 512.0f) - mu * mu;
    eMu[tid] = mu;
    eRs[tid] = 1.0f / sqrtf(var + (1e-5f * 4096.0f * 4096.0f));
  }
  __syncthreads();

  // LN + exact-erf GELU + per-wave partial logits (per-r accumulation)
#pragma unroll
  for (int m = 0; m < 4; ++m) {
    int rb = m * 16 + l4 * 4;
#pragma unroll
    for (int r = 0; r < 4; ++r) {
      float mu_r = eMu[rb + r];
      float rs_r = eRs[rb + r];
      float lg[8];
#pragma unroll
      for (int e = 0; e < 8; ++e) lg[e] = 0.0f;
#pragma unroll
      for (int n = 0; n < 4; ++n) {
        int col = wv * 64 + n * 16 + l15;
        float hn = (acc[m][n][r] - mu_r) * rs_r;
        float y = fmaf(hn, lw[n], lb[n]);
        float g = 0.5f * y * (1.0f + erff(y * 0.70710678118654752440f));
        float4 w0 = *(const float4*)&eW2T[col * 12];
        float4 w1 = *(const float4*)&eW2T[col * 12 + 4];
        lg[0] = fmaf(g, w0.x, lg[0]);
        lg[1] = fmaf(g, w0.y, lg[1]);
        lg[2] = fmaf(g, w0.z, lg[2]);
        lg[3] = fmaf(g, w0.w, lg[3]);
        lg[4] = fmaf(g, w1.x, lg[4]);
        lg[5] = fmaf(g, w1.y, lg[5]);
        lg[6] = fmaf(g, w1.z, lg[6]);
        lg[7] = fmaf(g, w1.w, lg[7]);
      }
#pragma unroll
      for (int d = 1; d < 16; d <<= 1)
#pragma unroll
        for (int e = 0; e < 8; ++e) lg[e] += __shfl_xor(lg[e], d);
      if (l15 == 0) {
#pragma unroll
        for (int e = 0; e < 8; ++e) eLog[(wv * 64 + rb + r) * 8 + e] = lg[e];
      }
    }
  }
  __syncthreads();

  // top-2 + sparse softmax + write + load-balance partials
  if (tid < BM) {
    float v[8];
#pragma unroll
    for (int e = 0; e < 8; ++e) {
      float s = b2[e];
#pragma unroll
      for (int w = 0; w < 8; ++w) s += eLog[(w * 64 + tid) * 8 + e];
      v[e] = s;
    }
    float m1 = v[0];
    int i1 = 0;
#pragma unroll
    for (int e = 1; e < 8; ++e)
      if (v[e] > m1) { m1 = v[e]; i1 = e; }   // strict >: lowest index wins ties
    float m2 = -3.0e38f;
    int i2 = -1;
#pragma unroll
    for (int e = 0; e < 8; ++e)
      if (e != i1 && v[e] > m2) { m2 = v[e]; i2 = e; }
    float dd = expf(m2 - m1);
    float inv = 1.0f / (1.0f + dd);
    float wA = inv, wB = dd * inv;
    float o[8];
#pragma unroll
    for (int e = 0; e < 8; ++e)
      o[e] = (e == i1) ? wA : ((e == i2) ? wB : 0.0f);
    float4* op = (float4*)&out[(row0 + tid) * 8];
    op[0] = (float4){o[0], o[1], o[2], o[3]};
    op[1] = (float4){o[4], o[5], o[6], o[7]};
    atomicAdd(&eFP[i1], 1.0f);
    atomicAdd(&eFP[i2], 1.0f);
    atomicAdd(&eFP[8 + i1], wA);
    atomicAdd(&eFP[8 + i2], wB);
  }
  __syncthreads();
  if (tid < 16) atomicAdd(&gacc[tid], eFP[tid]);
}

// ---- finalize load-balance loss --------------------------------------------
__global__ void lb_final(const float* __restrict__ gacc, float* __restrict__ out) {
  if (threadIdx.x == 0) {
    const float invB = 1.0f / 65536.0f;
    float s = 0.0f;
#pragma unroll
    for (int e = 0; e < 8; ++e) s += (gacc[e] * invB) * (gacc[8 + e] * invB);
    out[(size_t)B_ROWS * E_DIM] = 0.01f * 8.0f * s;
  }
}

// ---- launch ----------------------------------------------------------------
extern "C" void kernel_launch(void* const* d_in, const int* in_sizes, int n_in,
                              void* d_out, int out_size, void* d_ws, size_t ws_size,
                              hipStream_t stream) {
  (void)in_sizes; (void)n_in; (void)out_size; (void)ws_size;
  const float* x = (const float*)d_in[0];
  const float* W1 = (const float*)d_in[1];
  const float* b1 = (const float*)d_in[2];
  const float* lnw = (const float*)d_in[3];
  const float* lnb = (const float*)d_in[4];
  const float* W2 = (const float*)d_in[5];
  const float* b2 = (const float*)d_in[6];
  float* out = (float*)d_out;
  f16* wh = (f16*)d_ws;
  f16* wl = wh + IMG_TOTAL;
  float* gacc = (float*)((char*)d_ws + GACC_OFF);  // ws needs ~2.1 MB

  zero_acc<<<1, 64, 0, stream>>>(gacc);
  prep_split<<<(D_DIM * H_DIM / 8) / 256, 256, 0, stream>>>(W1, wh, wl);
  fused_main<<<B_ROWS / BM, THREADS, 0, stream>>>(x, wh, wl, b1, lnw, lnb, W2, b2,
                                                  out, gacc);
  lb_final<<<1, 64, 0, stream>>>(gacc, out);
}